// Round 11
// baseline (297.215 us; speedup 1.0000x reference)
//
#include <hip/hip_runtime.h>

// HashRouter via MFMA bf16 hi/lo split GEMM (fp32 ~= hi+lo; hh+hl+lh;
// error ~1e-5 << TH=5e-5, borderliners re-checked exact in fp64).
// R14: asm-pinned software pipeline. R12's C++ named-buffer pipeline was
// DELETED by the compiler (VGPR=68 proves it: the 120-reg pipeline can't
// exist in 68; loads were sunk to consumers, prefetch distance ~0, so
// R12 ~= R11: 162 us, VALUBusy 18%, MfmaUtil 3%, waves stalled ~85% on
// exposed L2/HBM latency). Fix per AITER pattern: global_load_dwordx4 as
// asm volatile (issue order pinned, cannot sink) + hand-counted
// s_waitcnt vmcnt(2) per step + sched_barrier(0) after each wait
// (rule #18). Queue discipline: per step issue B(ks+1) x8 THEN A(ks+2) x2
// -> newest-2 are always the A-pair -> vmcnt(2) guarantees B(ks)+A(ks)
// landed; B covered ~1 step (~500cy >= L2), A ~2 steps (~1000cy >= HBM).
// No compiler VMEM inside the loop (accounting exact); vmcnt(0) at step 15
// drains before the epilogue's normal loads. Addressing: SGPR base pair +
// 32-bit voffset + imm offset ks*128(+16) <= 1936 < 4096 (13-bit signed).
// Layout facts (verified absmax=0, R11/R12): operand row = lane&15,
// k-slot order self-cancelling, C/D = D[tok=(lane>>4)*4+r][j=16*jt+(lane&15)].

constexpr int H_DIM  = 2048;
constexpr int NJ     = 64;
constexpr int TOKB   = 16;      // tokens per block
constexpr int KW     = 512;     // K-span per wave
constexpr int KSTEPS = KW / 32; // 16 MFMA K-steps per wave

typedef __attribute__((ext_vector_type(8))) short  bf16x8;
typedef __attribute__((ext_vector_type(4))) float  f32x4;

struct raw8  { f32x4 lo, hi; };
struct bquad { raw8 b0, b1, b2, b3; };

__device__ __forceinline__ unsigned int bf16rne(float f) {
    unsigned int u = __float_as_uint(f);
    return (u + 0x7FFFu + ((u >> 16) & 1u)) >> 16;   // RNE, finite inputs
}

// fp32[8] -> bf16 hi (truncated top16, exact residual) + bf16 lo (RNE).
__device__ __forceinline__ void split8(const f32x4 a0, const f32x4 a1,
                                       bf16x8& hi, bf16x8& lo) {
    union { bf16x8 v; unsigned int u[4]; } H, L;
    const unsigned int u0 = __float_as_uint(a0.x), u1 = __float_as_uint(a0.y);
    const unsigned int u2 = __float_as_uint(a0.z), u3 = __float_as_uint(a0.w);
    const unsigned int u4 = __float_as_uint(a1.x), u5 = __float_as_uint(a1.y);
    const unsigned int u6 = __float_as_uint(a1.z), u7 = __float_as_uint(a1.w);
    H.u[0] = (u0 >> 16) | (u1 & 0xFFFF0000u);
    H.u[1] = (u2 >> 16) | (u3 & 0xFFFF0000u);
    H.u[2] = (u4 >> 16) | (u5 & 0xFFFF0000u);
    H.u[3] = (u6 >> 16) | (u7 & 0xFFFF0000u);
    const float l0 = a0.x - __uint_as_float(u0 & 0xFFFF0000u);
    const float l1 = a0.y - __uint_as_float(u1 & 0xFFFF0000u);
    const float l2 = a0.z - __uint_as_float(u2 & 0xFFFF0000u);
    const float l3 = a0.w - __uint_as_float(u3 & 0xFFFF0000u);
    const float l4 = a1.x - __uint_as_float(u4 & 0xFFFF0000u);
    const float l5 = a1.y - __uint_as_float(u5 & 0xFFFF0000u);
    const float l6 = a1.z - __uint_as_float(u6 & 0xFFFF0000u);
    const float l7 = a1.w - __uint_as_float(u7 & 0xFFFF0000u);
    L.u[0] = bf16rne(l0) | (bf16rne(l1) << 16);
    L.u[1] = bf16rne(l2) | (bf16rne(l3) << 16);
    L.u[2] = bf16rne(l4) | (bf16rne(l5) << 16);
    L.u[3] = bf16rne(l6) | (bf16rne(l7) << 16);
    hi = H.v; lo = L.v;
}

// Pinned 16B global load: SGPR base + VGPR byte-offset + literal imm offset.
#define GLOAD(dst, BASE, VOFF, IMM) \
    asm volatile("global_load_dwordx4 %0, %1, %2 offset:%c3" \
                 : "=v"(dst) : "v"(VOFF), "s"(BASE), "n"(IMM))

#define ISSUE_A(AR, kk) do { \
    GLOAD(AR.lo, x, voffA, (kk) * 128);      \
    GLOAD(AR.hi, x, voffA, (kk) * 128 + 16); } while (0)

#define ISSUE_B(BQ, kk) do { \
    GLOAD(BQ.b0.lo, w, voffB0, (kk) * 128); GLOAD(BQ.b0.hi, w, voffB0, (kk) * 128 + 16); \
    GLOAD(BQ.b1.lo, w, voffB1, (kk) * 128); GLOAD(BQ.b1.hi, w, voffB1, (kk) * 128 + 16); \
    GLOAD(BQ.b2.lo, w, voffB2, (kk) * 128); GLOAD(BQ.b2.hi, w, voffB2, (kk) * 128 + 16); \
    GLOAD(BQ.b3.lo, w, voffB3, (kk) * 128); GLOAD(BQ.b3.hi, w, voffB3, (kk) * 128 + 16); } while (0)

#define JT_STEP(jt, BRV) { \
    bf16x8 BH, BL; split8(BRV.lo, BRV.hi, BH, BL); \
    acc[jt] = __builtin_amdgcn_mfma_f32_16x16x32_bf16(AL, BH, acc[jt], 0, 0, 0); \
    acc[jt] = __builtin_amdgcn_mfma_f32_16x16x32_bf16(AH, BL, acc[jt], 0, 0, 0); \
    acc[jt] = __builtin_amdgcn_mfma_f32_16x16x32_bf16(AH, BH, acc[jt], 0, 0, 0); }

// One K-step. ks is a LITERAL (imm offsets must fold). vmcnt(2): all but the
// newest 2 (the in-flight A-pair) have landed -> A(ks), B(ks) ready.
#define STEP(ks, AR, BC, BN) do { \
    if ((ks) < KSTEPS - 1) asm volatile("s_waitcnt vmcnt(2)" ::: "memory"); \
    else                   asm volatile("s_waitcnt vmcnt(0)" ::: "memory"); \
    __builtin_amdgcn_sched_barrier(0); \
    bf16x8 AH, AL; split8(AR.lo, AR.hi, AH, AL); \
    if ((ks) + 1 < KSTEPS) { ISSUE_B(BN, (ks) + 1); } \
    if ((ks) + 2 < KSTEPS) { ISSUE_A(AR, (ks) + 2); } \
    JT_STEP(0, BC.b0); JT_STEP(1, BC.b1); JT_STEP(2, BC.b2); JT_STEP(3, BC.b3); \
} while (0)

__global__ __launch_bounds__(256, 2) void hash_mfma_kernel(
    const float* __restrict__ x,             // [T, H] fp32
    const float* __restrict__ w,             // [64, H] fp32
    const float* __restrict__ b,             // [64]
    float* __restrict__ out,                 // [2T | 2T | 64T]
    int T)
{
    __shared__ float red[3 * 64 * 16];       // 12 KB cross-wave reduce

    const int tid  = threadIdx.x;
    const int wv   = tid >> 6;               // wave = k-quarter (0..3)
    const int lane = tid & 63;
    const int row  = lane & 15;              // A row (token) / B row (j%16)
    const int kq   = lane >> 4;              // k-octet group within K=32
    const int tokB = blockIdx.x * TOKB;

    // Byte offsets (fit u32: max ~134 MB). k = wv*512 + ks*32 + kq*8 + e.
    const unsigned int voffA  = (((unsigned)(tokB + row) * H_DIM) + wv * KW + kq * 8) * 4u;
    const unsigned int voffB0 = (((unsigned)(0 * 16 + row) * H_DIM) + wv * KW + kq * 8) * 4u;
    const unsigned int voffB1 = voffB0 + 16u * H_DIM * 4u;
    const unsigned int voffB2 = voffB0 + 32u * H_DIM * 4u;
    const unsigned int voffB3 = voffB0 + 48u * H_DIM * 4u;

    f32x4 acc[4];
#pragma unroll
    for (int jt = 0; jt < 4; ++jt) acc[jt] = (f32x4){0.f, 0.f, 0.f, 0.f};

    raw8  arE, arO;
    bquad brE, brO;

    // Prologue: B(0) x8 first, then A(0), A(1) (newest-2 = A(1) pair).
    ISSUE_B(brE, 0);
    ISSUE_A(arE, 0);
    ISSUE_A(arO, 1);

    // ---- Fully-unrolled pinned pipeline: no LDS, no barriers.
    STEP( 0, arE, brE, brO);  STEP( 1, arO, brO, brE);
    STEP( 2, arE, brE, brO);  STEP( 3, arO, brO, brE);
    STEP( 4, arE, brE, brO);  STEP( 5, arO, brO, brE);
    STEP( 6, arE, brE, brO);  STEP( 7, arO, brO, brE);
    STEP( 8, arE, brE, brO);  STEP( 9, arO, brO, brE);
    STEP(10, arE, brE, brO);  STEP(11, arO, brO, brE);
    STEP(12, arE, brE, brO);  STEP(13, arO, brO, brE);
    STEP(14, arE, brE, brO);  STEP(15, arO, brO, brE);

    // ---- Cross-wave k-quarter reduce (the only barrier).
    if (wv) {
        float* rp = red + ((wv - 1) * 64 + lane) * 16;
#pragma unroll
        for (int jt = 0; jt < 4; ++jt) *(f32x4*)(rp + jt * 4) = acc[jt];
    }
    __syncthreads();

    if (wv == 0) {
#pragma unroll
        for (int w2 = 0; w2 < 3; ++w2)
#pragma unroll
            for (int jt = 0; jt < 4; ++jt) {
                const f32x4 t = *(const f32x4*)(red + (w2 * 64 + lane) * 16 + jt * 4);
                acc[jt].x += t.x; acc[jt].y += t.y; acc[jt].z += t.z; acc[jt].w += t.w;
            }

        float bias[4];
#pragma unroll
        for (int jt = 0; jt < 4; ++jt) bias[jt] = b[jt * 16 + row];

        // C/D layout (m89): lane holds D[tok=(lane>>4)*4+r][j=jt*16+(lane&15)].
        // Sign -> ballot -> per-token popcount; lane t<16 owns token t.
        const float TH = 5e-5f;
        int c0 = 0, c1 = 0;
        const int myg = (lane >> 2) & 3;     // &3: no shift-UB for lane>=16
        const int myr = lane & 3;
#pragma unroll
        for (int jt = 0; jt < 4; ++jt)
#pragma unroll
            for (int r = 0; r < 4; ++r) {
                const float h = acc[jt][r] + bias[jt];
                bool pos;
                if (__builtin_expect(fabsf(h) < TH, 0)) {
                    // split error ~1e-5 < TH: exact fp64 recheck (rare).
                    const float* xr = x + (size_t)(tokB + (lane >> 4) * 4 + r) * H_DIM;
                    const float* wr = w + (size_t)(jt * 16 + row) * H_DIM;
                    double sd = (double)bias[jt];
                    for (int k = 0; k < H_DIM; ++k)
                        sd += (double)xr[k] * (double)wr[k];
                    pos = (sd > 0.0);
                } else {
                    pos = (h > 0.0f);
                }
                const unsigned long long bal = __ballot(pos);
                const int add = ((myr == r) ? 1 : 0) *
                    __popc((unsigned int)((bal >> (myg * 16)) & 0xFFFFu));
                if (jt < 2) c0 += add; else c1 += add;
            }

        if (lane < TOKB) {
            const int t  = tokB + lane;
            const int i1 = c1 + ((c1 == c0) ? 1 : 0);
            float2 wq; wq.x = 0.5f; wq.y = 0.5f;
            *(float2*)(out + 2 * (size_t)t) = wq;
            float2 iq; iq.x = (float)c0; iq.y = (float)i1;
            *(float2*)(out + 2 * (size_t)T + 2 * (size_t)t) = iq;
        }
    }

    // router_logits = 0: 16 tok x 64 = 1024 floats = 256 f32x4, one/thread.
    f32x4 z = (f32x4){0.f, 0.f, 0.f, 0.f};
    *(f32x4*)(out + 4 * (size_t)T + (size_t)tokB * NJ + (size_t)tid * 4) = z;
}

extern "C" void kernel_launch(void* const* d_in, const int* in_sizes, int n_in,
                              void* d_out, int out_size, void* d_ws, size_t ws_size,
                              hipStream_t stream) {
    const float* x = (const float*)d_in[0];
    const float* w = (const float*)d_in[1];
    const float* b = (const float*)d_in[2];
    float* out = (float*)d_out;
    const int T = in_sizes[0] / H_DIM;               // 16384
    hash_mfma_kernel<<<dim3(T / TOKB), dim3(256), 0, stream>>>(x, w, b, out, T);
}